// Round 5
// baseline (196.142 us; speedup 1.0000x reference)
//
#include <hip/hip_runtime.h>
#include <math.h>

namespace {
constexpr int kB = 524288;
constexpr int kC = 128;
constexpr int kBlocks = 2048;
constexpr int kThreads = 256;
constexpr int kWavesPerBlock = kThreads / 64;          // 4
constexpr int kHalves = kBlocks * kWavesPerBlock * 2;  // 16384 half-waves
static_assert(kB % kHalves == 0, "exact tiling");      // 32 rows per half-wave

struct Partial {
  float sum;     // sum of t = y*log(x) over this block's rows (un-negated)
  float maxv;    // max of per-row loss (-row_sum)
  int   maxidx;  // first index attaining maxv
  int   pad;
};

__device__ inline float row_from_elems(const float4& xv, const float4& yv) {
  float t0 = yv.x * __logf(xv.x);
  float t1 = yv.y * __logf(xv.y);
  float t2 = yv.z * __logf(xv.z);
  float t3 = yv.w * __logf(xv.w);
  // nansum semantics: NaN terms count as 0
  t0 = (t0 == t0) ? t0 : 0.0f;
  t1 = (t1 == t1) ? t1 : 0.0f;
  t2 = (t2 == t2) ? t2 : 0.0f;
  t3 = (t3 == t3) ? t3 : 0.0f;
  return (t0 + t1) + (t2 + t3);
}

__device__ inline float half_reduce(float r) {
  // reduce across the 32 lanes of this half-wave (masks 1..16 stay in-half)
#pragma unroll
  for (int m = 1; m <= 16; m <<= 1) r += __shfl_xor(r, m, 64);
  return r;
}
}  // namespace

// Single fused kernel: grid-wide partials + last-block-done finalization.
__global__ __launch_bounds__(kThreads) void nll_fused(
    const float* __restrict__ x, const float* __restrict__ y,
    float* __restrict__ out, Partial* __restrict__ part,
    int* __restrict__ counter) {
  const int tid = threadIdx.x;
  const int waveInBlock = tid >> 6;
  const int half = (tid >> 5) & 1;
  const int lane32 = tid & 31;
  const int halfId = (blockIdx.x * kWavesPerBlock + waveInBlock) * 2 + half;

  float lsum = 0.0f;        // thread-local sum of t
  float bestv = -INFINITY;  // running row-loss max
  int bestidx = 0x7fffffff;

  for (int row = halfId; row < kB; row += kHalves) {
    // 32 lanes x float4 = 128 elems = one full row, perfectly coalesced.
    const float4 xv = *((const float4*)(x + (size_t)row * kC) + lane32);
    const float4 yv = *((const float4*)(y + (size_t)row * kC) + lane32);
    const float p = row_from_elems(xv, yv);
    lsum += p;

    const float rowv = -half_reduce(p);
    // Rows strictly increase per lane: strict '>' keeps the FIRST index.
    if (rowv > bestv) { bestv = rowv; bestidx = row; }
  }

  // wave-level reduce (64 lanes); min-index tie-break preserves 'first'.
#pragma unroll
  for (int m = 1; m <= 32; m <<= 1) {
    lsum += __shfl_xor(lsum, m, 64);
    const float ov = __shfl_xor(bestv, m, 64);
    const int oi = __shfl_xor(bestidx, m, 64);
    if (ov > bestv || (ov == bestv && oi < bestidx)) {
      bestv = ov;
      bestidx = oi;
    }
  }

  __shared__ float s_sum[kWavesPerBlock];
  __shared__ float s_max[kWavesPerBlock];
  __shared__ int s_idx[kWavesPerBlock];
  if ((tid & 63) == 0) {
    s_sum[waveInBlock] = lsum;
    s_max[waveInBlock] = bestv;
    s_idx[waveInBlock] = bestidx;
  }
  __syncthreads();

  __shared__ bool s_isLast;
  if (tid == 0) {
    float bs = 0.0f;
    float bm = -INFINITY;
    int bi = 0x7fffffff;
#pragma unroll
    for (int w = 0; w < kWavesPerBlock; ++w) {
      bs += s_sum[w];
      if (s_max[w] > bm || (s_max[w] == bm && s_idx[w] < bi)) {
        bm = s_max[w];
        bi = s_idx[w];
      }
    }
    Partial p;
    p.sum = bs;
    p.maxv = bm;
    p.maxidx = bi;
    p.pad = 0;
    part[blockIdx.x] = p;
    __threadfence();  // release: part[] visible device-wide before counter
    const int prev = atomicAdd(counter, 1);  // device scope by default
    s_isLast = (prev == kBlocks - 1);
  }
  __syncthreads();
  if (!s_isLast) return;

  // ---- Last block finalizes (deterministic: fixed-order reduction) ----
  __threadfence();  // acquire: make all blocks' part[] writes visible

  double ds = 0.0;
  float bm = -INFINITY;
  int bi = 0x7fffffff;
  for (int i = tid; i < kBlocks; i += kThreads) {  // fixed strided order
    const Partial p = part[i];
    ds += (double)p.sum;
    if (p.maxv > bm || (p.maxv == bm && p.maxidx < bi)) {
      bm = p.maxv;
      bi = p.maxidx;
    }
  }
#pragma unroll
  for (int m = 1; m <= 32; m <<= 1) {
    ds += __shfl_xor(ds, m, 64);
    const float ov = __shfl_xor(bm, m, 64);
    const int oi = __shfl_xor(bi, m, 64);
    if (ov > bm || (ov == bm && oi < bi)) {
      bm = ov;
      bi = oi;
    }
  }
  __shared__ double f_sum[kWavesPerBlock];
  __shared__ float f_max[kWavesPerBlock];
  __shared__ int f_idx[kWavesPerBlock];
  if ((tid & 63) == 0) {
    f_sum[waveInBlock] = ds;
    f_max[waveInBlock] = bm;
    f_idx[waveInBlock] = bi;
  }
  __syncthreads();
  if (tid == 0) {
    double S = 0.0;
    float M = -INFINITY;
    int I = 0x7fffffff;
#pragma unroll
    for (int w = 0; w < kWavesPerBlock; ++w) {
      S += f_sum[w];
      if (f_max[w] > M || (f_max[w] == M && f_idx[w] < I)) {
        M = f_max[w];
        I = f_idx[w];
      }
    }
    out[0] = (float)(-S / (double)kB);  // mean of per-row loss
    out[1] = M;                         // max loss
    out[2] = (float)I;                  // first argmax index
  }
}

extern "C" void kernel_launch(void* const* d_in, const int* in_sizes, int n_in,
                              void* d_out, int out_size, void* d_ws,
                              size_t ws_size, hipStream_t stream) {
  (void)in_sizes;
  (void)n_in;
  (void)out_size;
  (void)ws_size;
  const float* x = (const float*)d_in[0];
  const float* y = (const float*)d_in[1];
  float* out = (float*)d_out;
  Partial* part = (Partial*)d_ws;
  int* counter = (int*)((char*)d_ws + kBlocks * sizeof(Partial));

  // Counter must be zero at every launch (d_ws is not re-poisoned between
  // replays); async memset is graph-capture legal.
  hipMemsetAsync(counter, 0, sizeof(int), stream);
  nll_fused<<<kBlocks, kThreads, 0, stream>>>(x, y, out, part, counter);
}

// Round 6
// 101.770 us; speedup vs baseline: 1.9273x; 1.9273x over previous
//
#include <hip/hip_runtime.h>
#include <math.h>

namespace {
constexpr int kB = 524288;
constexpr int kC = 128;
constexpr int kBlocks = 2048;
constexpr int kThreads = 256;
constexpr int kWavesPerBlock = kThreads / 64;          // 4
constexpr int kHalves = kBlocks * kWavesPerBlock * 2;  // 16384 half-waves
static_assert(kB % kHalves == 0, "exact tiling");      // 32 rows per half-wave

struct Partial {
  float sum;     // sum of t = y*log(x) over this block's rows (un-negated)
  float maxv;    // max of per-row loss (-row_sum)
  int   maxidx;  // first index attaining maxv
  int   pad;
};

__device__ inline float row_from_elems(const float4& xv, const float4& yv) {
  float t0 = yv.x * __logf(xv.x);
  float t1 = yv.y * __logf(xv.y);
  float t2 = yv.z * __logf(xv.z);
  float t3 = yv.w * __logf(xv.w);
  // nansum semantics: NaN terms count as 0
  t0 = (t0 == t0) ? t0 : 0.0f;
  t1 = (t1 == t1) ? t1 : 0.0f;
  t2 = (t2 == t2) ? t2 : 0.0f;
  t3 = (t3 == t3) ? t3 : 0.0f;
  return (t0 + t1) + (t2 + t3);
}

__device__ inline float half_reduce(float r) {
  // reduce across the 32 lanes of this half-wave (masks 1..16 stay in-half)
#pragma unroll
  for (int m = 1; m <= 16; m <<= 1) r += __shfl_xor(r, m, 64);
  return r;
}
}  // namespace

// Stage 1: unchanged from the best-measured R0 structure.
__global__ __launch_bounds__(kThreads) void nll_stage1(
    const float* __restrict__ x, const float* __restrict__ y,
    Partial* __restrict__ part) {
  const int tid = threadIdx.x;
  const int waveInBlock = tid >> 6;
  const int half = (tid >> 5) & 1;
  const int lane32 = tid & 31;
  const int halfId = (blockIdx.x * kWavesPerBlock + waveInBlock) * 2 + half;

  float lsum = 0.0f;        // thread-local sum of t
  float bestv = -INFINITY;  // running row-loss max
  int bestidx = 0x7fffffff;

  for (int row = halfId; row < kB; row += kHalves) {
    // 32 lanes x float4 = 128 elems = one full row, perfectly coalesced.
    const float4 xv = *((const float4*)(x + (size_t)row * kC) + lane32);
    const float4 yv = *((const float4*)(y + (size_t)row * kC) + lane32);
    const float p = row_from_elems(xv, yv);
    lsum += p;

    const float rowv = -half_reduce(p);
    // Rows strictly increase per lane: strict '>' keeps the FIRST index.
    if (rowv > bestv) { bestv = rowv; bestidx = row; }
  }

  // wave-level reduce (64 lanes); min-index tie-break preserves 'first'.
#pragma unroll
  for (int m = 1; m <= 32; m <<= 1) {
    lsum += __shfl_xor(lsum, m, 64);
    const float ov = __shfl_xor(bestv, m, 64);
    const int oi = __shfl_xor(bestidx, m, 64);
    if (ov > bestv || (ov == bestv && oi < bestidx)) {
      bestv = ov;
      bestidx = oi;
    }
  }

  __shared__ float s_sum[kWavesPerBlock];
  __shared__ float s_max[kWavesPerBlock];
  __shared__ int s_idx[kWavesPerBlock];
  if ((tid & 63) == 0) {
    s_sum[waveInBlock] = lsum;
    s_max[waveInBlock] = bestv;
    s_idx[waveInBlock] = bestidx;
  }
  __syncthreads();
  if (tid == 0) {
    float bs = 0.0f;
    float bm = -INFINITY;
    int bi = 0x7fffffff;
#pragma unroll
    for (int w = 0; w < kWavesPerBlock; ++w) {
      bs += s_sum[w];
      if (s_max[w] > bm || (s_max[w] == bm && s_idx[w] < bi)) {
        bm = s_max[w];
        bi = s_idx[w];
      }
    }
    part[blockIdx.x].sum = bs;
    part[blockIdx.x].maxv = bm;
    part[blockIdx.x].maxidx = bi;
    part[blockIdx.x].pad = 0;
  }
}

// Stage 2: widened to 256 threads (was 1 wave). Each thread owns 8 partials
// in fixed strided order; 8 independent 16B loads give MLP; deterministic.
__global__ __launch_bounds__(kThreads) void nll_stage2(
    const Partial* __restrict__ part, float* __restrict__ out) {
  const int tid = threadIdx.x;
  const int waveInBlock = tid >> 6;

  double s = 0.0;
  float bm = -INFINITY;
  int bi = 0x7fffffff;
#pragma unroll
  for (int k = 0; k < kBlocks / kThreads; ++k) {  // 8 iterations, fixed order
    const Partial p = part[tid + k * kThreads];
    s += (double)p.sum;
    if (p.maxv > bm || (p.maxv == bm && p.maxidx < bi)) {
      bm = p.maxv;
      bi = p.maxidx;
    }
  }
#pragma unroll
  for (int m = 1; m <= 32; m <<= 1) {
    s += __shfl_xor(s, m, 64);
    const float ov = __shfl_xor(bm, m, 64);
    const int oi = __shfl_xor(bi, m, 64);
    if (ov > bm || (ov == bm && oi < bi)) {
      bm = ov;
      bi = oi;
    }
  }

  __shared__ double f_sum[kWavesPerBlock];
  __shared__ float f_max[kWavesPerBlock];
  __shared__ int f_idx[kWavesPerBlock];
  if ((tid & 63) == 0) {
    f_sum[waveInBlock] = s;
    f_max[waveInBlock] = bm;
    f_idx[waveInBlock] = bi;
  }
  __syncthreads();
  if (tid == 0) {
    double S = 0.0;
    float M = -INFINITY;
    int I = 0x7fffffff;
#pragma unroll
    for (int w = 0; w < kWavesPerBlock; ++w) {
      S += f_sum[w];
      if (f_max[w] > M || (f_max[w] == M && f_idx[w] < I)) {
        M = f_max[w];
        I = f_idx[w];
      }
    }
    out[0] = (float)(-S / (double)kB);  // mean of per-row loss
    out[1] = M;                         // max loss
    out[2] = (float)I;                  // first argmax index
  }
}

extern "C" void kernel_launch(void* const* d_in, const int* in_sizes, int n_in,
                              void* d_out, int out_size, void* d_ws,
                              size_t ws_size, hipStream_t stream) {
  (void)in_sizes;
  (void)n_in;
  (void)out_size;
  (void)ws_size;
  const float* x = (const float*)d_in[0];
  const float* y = (const float*)d_in[1];
  float* out = (float*)d_out;
  Partial* part = (Partial*)d_ws;

  nll_stage1<<<kBlocks, kThreads, 0, stream>>>(x, y, part);
  nll_stage2<<<1, kThreads, 0, stream>>>(part, out);
}